// Round 7
// baseline (417.762 us; speedup 1.0000x reference)
//
#include <hip/hip_runtime.h>
#include <math.h>

// Problem constants
#define BB    256
#define NMAX  512
#define HH    256   // H
#define CC    64    // C
#define HID   512
#define NEGV  -1000000000.0f
#define MT    64    // d-rows per mlp block
#define NW    8     // waves per block (512 threads)
#define SA_LD 264   // A-tile leading dim: 256 + 8 pad (bf16 elems)
#define TILE  512   // ushorts per swizzled (16n x 32k) weight tile = 1KB
#define KSTR  (32 * TILE)  // ushorts per kb slab (32 n-tiles)

typedef __attribute__((ext_vector_type(8))) short short8;   // 8 bf16 = 4 VGPRs
typedef __attribute__((ext_vector_type(4))) float floatx4;  // MFMA C/D

// Native cast -> v_cvt_pk_bf16_f32 pairs (RNE, identical numerics to manual
// round-to-nearest-even bit math).
__device__ inline ushort f2bf(float x) {
    __bf16 b = (__bf16)x;
    return __builtin_bit_cast(ushort, b);
}

// ---------------------------------------------------------------------------
// Fused prep kernel, grid = 512 blocks x 512 threads (unchanged from R10):
//   blocks [0,128):   convert W1 k-rows [0,512) -> swizzled lane-order bf16
//   blocks [128,256): convert W2 -> swizzled lane-order bf16
//   blocks [256,512): per-batch base vector v_b (fp32 exact), 1 col/thread
// ---------------------------------------------------------------------------
__global__ __launch_bounds__(512) void prep_kernel(
    const float* __restrict__ W1, const float* __restrict__ W2,
    ushort* __restrict__ Wt1s, ushort* __restrict__ Wt2s,
    const float* __restrict__ nodes_hv, const float* __restrict__ class_cond,
    const float* __restrict__ b1,
    const int* __restrict__ dirns, const int* __restrict__ node_counts,
    float* __restrict__ v_ws)
{
    const int blk = blockIdx.x;
    const int t = threadIdx.x;

    __shared__ float s_conv[32][68];
    __shared__ float s_src[HH];
    __shared__ float s_cc[CC];

    if (blk < 256) {
        const float* W = (blk < 128) ? W1 : W2;
        ushort* out    = (blk < 128) ? Wt1s : Wt2s;
        const int bb  = blk & 127;
        const int kb  = bb >> 3, ntg = bb & 7;

        if (t < 256) {
            const int kl = t >> 3, nn = (t & 7) * 8;
            const float* src = W + (size_t)(kb * 32 + kl) * HID + ntg * 64 + nn;
            *(float4*)&s_conv[kl][nn]     = *(const float4*)src;
            *(float4*)&s_conv[kl][nn + 4] = *(const float4*)(src + 4);
        }
        __syncthreads();

        if (t < 256) {
            const int ntl = t >> 6, ls = t & 63;
            const int qs = ls >> 4, l15s = ls & 15;
            short8 o;
            #pragma unroll
            for (int j = 0; j < 8; ++j)
                o[j] = (short)f2bf(s_conv[qs * 8 + j][ntl * 16 + l15s]);
            const int nt = ntg * 4 + ntl;
            *(short8*)(out + ((size_t)(kb * 32 + nt)) * TILE + ls * 8) = o;
        }
    } else {
        const int b = blk - 256;
        const int nc   = node_counts[b];
        const int dirn = dirns[b];
        const int src_idx = nc - 1;

        if (t < HH) s_src[t] = nodes_hv[((size_t)b * NMAX + src_idx) * HH + t];
        else if (t < HH + CC) s_cc[t - HH] = class_cond[b * CC + (t - HH)];
        __syncthreads();

        const int srcoff = (dirn == 1) ? HH : 0;

        const int j = t;              // one HID column per thread
        float acc0 = b1[j];

        #pragma unroll 8
        for (int r = 0; r < HH; ++r)
            acc0 += s_src[r] * W1[(size_t)(srcoff + r) * HID + j];
        #pragma unroll 8
        for (int c = 0; c < CC; ++c)
            acc0 += s_cc[c] * W1[(size_t)(2 * HH + c) * HID + j];

        v_ws[b * HID + j] = acc0;
    }
}

// ---------------------------------------------------------------------------
// Kernel 2: MFMA MLP, M=64, 512 threads (8 waves). grid = (NMAX/MT, B).
// R12: split-n passes. Each layer's 4 n-tiles/wave are computed as TWO
// sequential passes of 2 n-tiles -> live accumulator halves (64 -> 32 AGPR).
// Pass-A L1 results are compressed to packed bf16 (16 VGPR) between passes;
// h1 LDS writes stay deferred until after the A-tile-read barrier. This frees
// ~30 regs inside the (512,4)=128 cap for an explicit depth-2 weight prefetch
// (3-buffer rotation, compile-time indices), attacking the K-step L2-latency
// exposure that pinned MfmaUtil at 27%. Numerics: identical MFMA chain per
// (mb, n-tile) and identical epilogue order -> bit-identical to R9/R10.
// R8 lesson stands: do NOT lower the reg cap below peak-live (spill = 12x).
// ---------------------------------------------------------------------------
__global__ __launch_bounds__(512, 4) void mlp2(
    const float* __restrict__ nodes_hv,
    const ushort* __restrict__ Wt1s, const ushort* __restrict__ Wt2s,
    const float* __restrict__ b2, const float* __restrict__ W3,
    const float* __restrict__ b3,
    const int* __restrict__ dirns, const int* __restrict__ node_counts,
    const float* __restrict__ v_ws, float* __restrict__ scores)
{
    const int b  = blockIdx.y;
    const int d0 = blockIdx.x * MT;
    const int t  = threadIdx.x;
    const int lane = t & 63, wv = t >> 6;     // wv in [0,8)
    const int l15 = lane & 15, q = lane >> 4;

    __shared__ ushort s_u[32768];   // 64 KB union

    const int nc = node_counts[b];

    // Block-uniform early exit: whole tile masked off
    if (d0 >= nc - 1) {
        if (t < MT) scores[b * NMAX + d0 + t] = NEGV;
        return;
    }

    // dirn==1: cand occupies x[0:256) -> W1 k-rows [0:256) -> kb0=0; else kb0=8
    const int kb0 = (dirns[b] == 1) ? 0 : 8;

    // v_b values for this wave's 4 n-cols (g = 0..3 -> n = wv*64 + g*16 + l15)
    float vws[4];
    #pragma unroll
    for (int g = 0; g < 4; ++g)
        vws[g] = v_ws[b * HID + wv * 64 + g * 16 + l15];

    // ---- stage cand tile (MT x 256 fp32 -> bf16 LDS, leading dim SA_LD) ----
    {
        const float4* src4 = (const float4*)nodes_hv + ((size_t)b * NMAX + d0) * (HH / 4);
        #pragma unroll
        for (int i = 0; i < (MT * HH / 4) / 512; ++i) {   // 8 iters
            int idx = t + i * 512;
            int row = idx >> 6, c4 = idx & 63;
            float4 v = src4[idx];
            ushort4 p;
            p.x = f2bf(v.x); p.y = f2bf(v.y); p.z = f2bf(v.z); p.w = f2bf(v.w);
            *(ushort4*)&s_u[row * SA_LD + c4 * 4] = p;
        }
    }
    __syncthreads();

    floatx4 acc[4][2];   // 32 AGPR — half the previous live accumulator

    // ---- layer 1 pass: 2 n-tiles (h*2, h*2+1), K = 256 (8 K-steps),
    //      depth-2 weight prefetch via 3-buffer rotation ----
    auto l1_pass = [&](int h) {
        #pragma unroll
        for (int mb = 0; mb < 4; ++mb)
            #pragma unroll
            for (int tn = 0; tn < 2; ++tn)
                acc[mb][tn] = (floatx4){0.f, 0.f, 0.f, 0.f};
        const ushort* wb = Wt1s + ((size_t)(kb0 * 32) + wv * 4 + h * 2) * TILE + lane * 8;
        short8 bw[3][2];
        #pragma unroll
        for (int pf = 0; pf < 2; ++pf) {
            bw[pf][0] = *(const short8*)(wb + (size_t)pf * KSTR);
            bw[pf][1] = *(const short8*)(wb + (size_t)pf * KSTR + TILE);
        }
        #pragma unroll
        for (int ks = 0; ks < 8; ++ks) {
            if (ks < 6) {
                bw[(ks + 2) % 3][0] = *(const short8*)(wb + (size_t)(ks + 2) * KSTR);
                bw[(ks + 2) % 3][1] = *(const short8*)(wb + (size_t)(ks + 2) * KSTR + TILE);
            }
            __builtin_amdgcn_s_setprio(1);
            #pragma unroll
            for (int mb = 0; mb < 4; ++mb) {
                const short8 a = *(const short8*)&s_u[(mb * 16 + l15) * SA_LD + ks * 32 + q * 8];
                acc[mb][0] = __builtin_amdgcn_mfma_f32_16x16x32_bf16(a, bw[ks % 3][0], acc[mb][0], 0, 0, 0);
                acc[mb][1] = __builtin_amdgcn_mfma_f32_16x16x32_bf16(a, bw[ks % 3][1], acc[mb][1], 0, 0, 0);
            }
            __builtin_amdgcn_s_setprio(0);
        }
    };

    l1_pass(0);

    // Compress pass-A result to packed relu'd bf16 (16 VGPR); frees acc for pass B.
    uint pkA[4][2][2];
    #pragma unroll
    for (int mb = 0; mb < 4; ++mb)
        #pragma unroll
        for (int tn = 0; tn < 2; ++tn) {
            const float v = vws[tn];          // g = tn for half A
            #pragma unroll
            for (int pr = 0; pr < 2; ++pr) {
                float x0 = acc[mb][tn][2 * pr]     + v; x0 = x0 > 0.f ? x0 : 0.f;
                float x1 = acc[mb][tn][2 * pr + 1] + v; x1 = x1 > 0.f ? x1 : 0.f;
                pkA[mb][tn][pr] = (uint)f2bf(x0) | ((uint)f2bf(x1) << 16);
            }
        }

    l1_pass(1);

    __syncthreads();   // all waves done reading cand tile before h1 overwrites union

    // ---- epilogue 1: h1 -> fragment-tiled LDS ----
    // g = tn_global: ks_w = wv*2 + (g>>1); qr = ((g&1)<<1)+(l15>>3); j_w = l15&7
    {
        const int j_w = l15 & 7;
        // half A (g = 0,1) from packed regs
        #pragma unroll
        for (int tn = 0; tn < 2; ++tn) {
            const int ks_w = wv * 2;
            const int qr   = (tn << 1) + (l15 >> 3);
            #pragma unroll
            for (int mb = 0; mb < 4; ++mb)
                #pragma unroll
                for (int r = 0; r < 4; ++r) {
                    ushort hv = (ushort)(pkA[mb][tn][r >> 1] >> ((r & 1) * 16));
                    s_u[((mb * 16 + ks_w) * 64 + qr * 16 + q * 4 + r) * 8 + j_w] = hv;
                }
        }
        // half B (g = 2,3) straight from acc
        #pragma unroll
        for (int tn = 0; tn < 2; ++tn) {
            const float v = vws[2 + tn];
            const int ks_w = wv * 2 + 1;
            const int qr   = (tn << 1) + (l15 >> 3);
            #pragma unroll
            for (int mb = 0; mb < 4; ++mb)
                #pragma unroll
                for (int r = 0; r < 4; ++r) {
                    float hf = acc[mb][tn][r] + v;
                    hf = hf > 0.f ? hf : 0.f;
                    s_u[((mb * 16 + ks_w) * 64 + qr * 16 + q * 4 + r) * 8 + j_w] = f2bf(hf);
                }
        }
    }
    __syncthreads();

    // ---- layer 2: two passes of 2 n-tiles over K = 512 (16 K-steps),
    //      depth-2 weight prefetch; epilogue folds into p between passes ----
    float p[4][4] = {{0,0,0,0},{0,0,0,0},{0,0,0,0},{0,0,0,0}};
    const int n0 = wv * 64;

    auto l2_pass = [&](int h) {
        #pragma unroll
        for (int mb = 0; mb < 4; ++mb)
            #pragma unroll
            for (int tn = 0; tn < 2; ++tn)
                acc[mb][tn] = (floatx4){0.f, 0.f, 0.f, 0.f};
        const ushort* wb = Wt2s + ((size_t)(wv * 4 + h * 2)) * TILE + lane * 8;
        short8 bw[3][2];
        #pragma unroll
        for (int pf = 0; pf < 2; ++pf) {
            bw[pf][0] = *(const short8*)(wb + (size_t)pf * KSTR);
            bw[pf][1] = *(const short8*)(wb + (size_t)pf * KSTR + TILE);
        }
        #pragma unroll
        for (int ks = 0; ks < 16; ++ks) {
            if (ks < 14) {
                bw[(ks + 2) % 3][0] = *(const short8*)(wb + (size_t)(ks + 2) * KSTR);
                bw[(ks + 2) % 3][1] = *(const short8*)(wb + (size_t)(ks + 2) * KSTR + TILE);
            }
            __builtin_amdgcn_s_setprio(1);
            #pragma unroll
            for (int mb = 0; mb < 4; ++mb) {
                const short8 a = *(const short8*)&s_u[((mb * 16 + ks) * 64 + lane) * 8];
                acc[mb][0] = __builtin_amdgcn_mfma_f32_16x16x32_bf16(a, bw[ks % 3][0], acc[mb][0], 0, 0, 0);
                acc[mb][1] = __builtin_amdgcn_mfma_f32_16x16x32_bf16(a, bw[ks % 3][1], acc[mb][1], 0, 0, 0);
            }
            __builtin_amdgcn_s_setprio(0);
        }
        // fold into p (same g-order as the old tn=0..3 loop)
        #pragma unroll
        for (int tn = 0; tn < 2; ++tn) {
            const int g = h * 2 + tn;
            const int n = n0 + g * 16 + l15;
            const float bb = b2[n];
            const float w3 = W3[n];
            #pragma unroll
            for (int mb = 0; mb < 4; ++mb)
                #pragma unroll
                for (int r = 0; r < 4; ++r) {
                    float hf = acc[mb][tn][r] + bb;
                    hf = hf > 0.f ? hf : 0.f;
                    p[mb][r] += hf * w3;
                }
        }
    };

    l2_pass(0);
    l2_pass(1);

    __syncthreads();   // h1 region dead; safe to reuse union for s_red
    float* s_red = (float*)s_u;   // [8 waves][MT]
    #pragma unroll
    for (int mb = 0; mb < 4; ++mb)
        #pragma unroll
        for (int r = 0; r < 4; ++r) {
            float v = p[mb][r];
            v += __shfl_xor(v, 1, 64);
            v += __shfl_xor(v, 2, 64);
            v += __shfl_xor(v, 4, 64);
            v += __shfl_xor(v, 8, 64);
            if (l15 == 0) s_red[wv * MT + mb * 16 + q * 4 + r] = v;
        }
    __syncthreads();
    if (t < MT) {
        float s = b3[0];
        #pragma unroll
        for (int w = 0; w < NW; ++w) s += s_red[w * MT + t];
        const int d = d0 + t;
        scores[b * NMAX + d] = (d < nc - 1) ? s : NEGV;
    }
}

// ---------------------------------------------------------------------------
// Kernel 3: per-batch masked log-softmax NLL. grid = B, block = 256.
// ---------------------------------------------------------------------------
__global__ __launch_bounds__(256) void loss_kernel(
    const float* __restrict__ scores, const int* __restrict__ dests,
    float* __restrict__ out)
{
    const int b = blockIdx.x;
    const int t = threadIdx.x;
    __shared__ float red[4];

    const float s0 = scores[b * NMAX + t];
    const float s1 = scores[b * NMAX + t + 256];

    const int lane = t & 63, wv = t >> 6;

    float mx = fmaxf(s0, s1);
    #pragma unroll
    for (int off = 32; off > 0; off >>= 1) mx = fmaxf(mx, __shfl_down(mx, off, 64));
    if (lane == 0) red[wv] = mx;
    __syncthreads();
    mx = fmaxf(fmaxf(red[0], red[1]), fmaxf(red[2], red[3]));
    __syncthreads();

    float e = __expf(s0 - mx) + __expf(s1 - mx);
    #pragma unroll
    for (int off = 32; off > 0; off >>= 1) e += __shfl_down(e, off, 64);
    if (lane == 0) red[wv] = e;
    __syncthreads();

    if (t == 0) {
        const float sum = red[0] + red[1] + red[2] + red[3];
        const float sd = scores[b * NMAX + dests[b]];
        out[b] = -(sd - mx - logf(sum));
    }
}

// ---------------------------------------------------------------------------
extern "C" void kernel_launch(void* const* d_in, const int* in_sizes, int n_in,
                              void* d_out, int out_size, void* d_ws, size_t ws_size,
                              hipStream_t stream) {
    const float* nodes_hv    = (const float*)d_in[0];
    const float* class_cond  = (const float*)d_in[1];
    const float* W1          = (const float*)d_in[2];
    const float* b1          = (const float*)d_in[3];
    const float* W2          = (const float*)d_in[4];
    const float* b2          = (const float*)d_in[5];
    const float* W3          = (const float*)d_in[6];
    const float* b3          = (const float*)d_in[7];
    const int*   dirns       = (const int*)d_in[8];
    const int*   node_counts = (const int*)d_in[9];
    const int*   dests       = (const int*)d_in[10];
    float* out = (float*)d_out;

    // ws layout (16B-aligned):
    //   Wt1s: 512 KiB | Wt2s: 512 KiB | v_ws: 512 KiB | scores: 512 KiB
    ushort* Wt1s   = (ushort*)d_ws;
    ushort* Wt2s   = Wt1s + 16 * KSTR;
    float*  v_ws   = (float*)(Wt2s + 16 * KSTR);
    float*  scores = v_ws + BB * HID;

    prep_kernel<<<512, 512, 0, stream>>>(W1, W2, Wt1s, Wt2s,
                                         nodes_hv, class_cond, b1,
                                         dirns, node_counts, v_ws);
    mlp2<<<dim3(NMAX / MT, BB), 512, 0, stream>>>(
        nodes_hv, Wt1s, Wt2s, b2, W3, b3, dirns, node_counts, v_ws, scores);
    loss_kernel<<<BB, 256, 0, stream>>>(scores, dests, out);
}

// Round 11
// 365.699 us; speedup vs baseline: 1.1424x; 1.1424x over previous
//
#include <hip/hip_runtime.h>
#include <math.h>

// Problem constants
#define BB    256
#define NMAX  512
#define HH    256   // H
#define CC    64    // C
#define HID   512
#define NEGV  -1000000000.0f
#define MT    64    // d-rows per mlp block
#define NW    8     // waves per block (512 threads)
#define SA_LD 264   // A-tile leading dim: 256 + 8 pad (bf16 elems)
#define TILE  512   // ushorts per swizzled (16n x 32k) weight tile = 1KB
#define KSTR  (32 * TILE)  // ushorts per kb slab (32 n-tiles)

typedef __attribute__((ext_vector_type(8))) short short8;   // 8 bf16 = 4 VGPRs
typedef __attribute__((ext_vector_type(4))) float floatx4;  // MFMA C/D

// Native cast -> v_cvt_pk_bf16_f32 pairs (RNE).
__device__ inline ushort f2bf(float x) {
    __bf16 b = (__bf16)x;
    return __builtin_bit_cast(ushort, b);
}

// ---------------------------------------------------------------------------
// Fused prep kernel, grid = 512 blocks x 512 threads (R10, verified):
//   blocks [0,128):   convert W1 k-rows [0,512) -> swizzled lane-order bf16
//   blocks [128,256): convert W2 -> swizzled lane-order bf16
//   blocks [256,512): per-batch base vector v_b (fp32 exact), 1 col/thread
// ---------------------------------------------------------------------------
__global__ __launch_bounds__(512) void prep_kernel(
    const float* __restrict__ W1, const float* __restrict__ W2,
    ushort* __restrict__ Wt1s, ushort* __restrict__ Wt2s,
    const float* __restrict__ nodes_hv, const float* __restrict__ class_cond,
    const float* __restrict__ b1,
    const int* __restrict__ dirns, const int* __restrict__ node_counts,
    float* __restrict__ v_ws)
{
    const int blk = blockIdx.x;
    const int t = threadIdx.x;

    __shared__ float s_conv[32][68];
    __shared__ float s_src[HH];
    __shared__ float s_cc[CC];

    if (blk < 256) {
        const float* W = (blk < 128) ? W1 : W2;
        ushort* out    = (blk < 128) ? Wt1s : Wt2s;
        const int bb  = blk & 127;
        const int kb  = bb >> 3, ntg = bb & 7;

        if (t < 256) {
            const int kl = t >> 3, nn = (t & 7) * 8;
            const float* src = W + (size_t)(kb * 32 + kl) * HID + ntg * 64 + nn;
            *(float4*)&s_conv[kl][nn]     = *(const float4*)src;
            *(float4*)&s_conv[kl][nn + 4] = *(const float4*)(src + 4);
        }
        __syncthreads();

        if (t < 256) {
            const int ntl = t >> 6, ls = t & 63;
            const int qs = ls >> 4, l15s = ls & 15;
            short8 o;
            #pragma unroll
            for (int j = 0; j < 8; ++j)
                o[j] = (short)f2bf(s_conv[qs * 8 + j][ntl * 16 + l15s]);
            const int nt = ntg * 4 + ntl;
            *(short8*)(out + ((size_t)(kb * 32 + nt)) * TILE + ls * 8) = o;
        }
    } else {
        const int b = blk - 256;
        const int nc   = node_counts[b];
        const int dirn = dirns[b];
        const int src_idx = nc - 1;

        if (t < HH) s_src[t] = nodes_hv[((size_t)b * NMAX + src_idx) * HH + t];
        else if (t < HH + CC) s_cc[t - HH] = class_cond[b * CC + (t - HH)];
        __syncthreads();

        const int srcoff = (dirn == 1) ? HH : 0;

        const int j = t;              // one HID column per thread
        float acc0 = b1[j];

        #pragma unroll 8
        for (int r = 0; r < HH; ++r)
            acc0 += s_src[r] * W1[(size_t)(srcoff + r) * HID + j];
        #pragma unroll 8
        for (int c = 0; c < CC; ++c)
            acc0 += s_cc[c] * W1[(size_t)(2 * HH + c) * HID + j];

        v_ws[b * HID + j] = acc0;
    }
}

// ---------------------------------------------------------------------------
// Fused loss tail (classic threadfence-reduction "last block" pattern):
// every block of batch b bumps cnt[b] after its scores are device-visible;
// the 8th computes masked log-softmax NLL from L2-hot scores. Runs only in
// the dead-register phase of mlp2 -> no K-loop regalloc impact (R8/R12
// lesson: mlp2's main body sits on the 128-reg cliff; don't touch it).
// ---------------------------------------------------------------------------
__device__ __forceinline__ void fused_loss_tail(
    int b, int t, float* __restrict__ scores, const int* __restrict__ dests,
    float* __restrict__ out, unsigned* __restrict__ cnt, ushort* s_u)
{
    __syncthreads();                  // all this block's score stores issued/drained
    int* flag = (int*)s_u;
    if (t == 0) {
        __threadfence();              // release: stores device-visible (cross-XCD)
        unsigned old = atomicAdd(&cnt[b], 1u);   // device-scope by default
        flag[0] = (old == (NMAX / MT) - 1) ? 1 : 0;
    }
    __syncthreads();
    const int isLast = flag[0];
    __syncthreads();
    if (!isLast) return;
    if (t == 0) __threadfence();      // acquire: invalidate stale cache lines
    __syncthreads();

    const int lane = t & 63, wv = t >> 6;
    float* red = (float*)s_u;         // 8 slots; flag slot dead by now

    const float s0 = scores[b * NMAX + t];   // one score per thread (512)
    float mx = s0;
    #pragma unroll
    for (int off = 32; off > 0; off >>= 1) mx = fmaxf(mx, __shfl_down(mx, off, 64));
    if (lane == 0) red[wv] = mx;
    __syncthreads();
    float m = red[0];
    #pragma unroll
    for (int w = 1; w < NW; ++w) m = fmaxf(m, red[w]);
    __syncthreads();                  // everyone read red before overwrite

    float e = __expf(s0 - m);
    #pragma unroll
    for (int off = 32; off > 0; off >>= 1) e += __shfl_down(e, off, 64);
    if (lane == 0) red[wv] = e;
    __syncthreads();
    if (t == 0) {
        float sum = 0.f;
        #pragma unroll
        for (int w = 0; w < NW; ++w) sum += red[w];
        const float sd = scores[b * NMAX + dests[b]];
        out[b] = -(sd - m - logf(sum));
    }
}

// ---------------------------------------------------------------------------
// Kernel 2: MFMA MLP, M=64, 512 threads (8 waves). grid = (NMAX/MT, B).
// Body = verified R10 (119 µs): full h1 in 64 KB LDS union, 2 blocks/CU,
// depth-1 register double-buffer of weight tiles, setprio around MFMA
// clusters, cvt_pk conversions. R13 adds only the fused loss tail.
// Register budget: acc(64 AGPR) + working(64 VGPR) = 128 = (512,4) cap.
// R8/R12 post-mortems: ANY restructure of acc/prefetch live ranges spills
// (12x / 2.2x slower). Do not touch the K-loop topology.
// ---------------------------------------------------------------------------
__global__ __launch_bounds__(512, 4) void mlp2(
    const float* __restrict__ nodes_hv,
    const ushort* __restrict__ Wt1s, const ushort* __restrict__ Wt2s,
    const float* __restrict__ b2, const float* __restrict__ W3,
    const float* __restrict__ b3,
    const int* __restrict__ dirns, const int* __restrict__ node_counts,
    const float* __restrict__ v_ws, float* __restrict__ scores,
    const int* __restrict__ dests, float* __restrict__ loss_out,
    unsigned* __restrict__ cnt, int fused)
{
    const int b  = blockIdx.y;
    const int d0 = blockIdx.x * MT;
    const int t  = threadIdx.x;
    const int lane = t & 63, wv = t >> 6;     // wv in [0,8)
    const int l15 = lane & 15, q = lane >> 4;

    __shared__ ushort s_u[32768];   // 64 KB union

    const int nc = node_counts[b];

    // Block-uniform early exit: whole tile masked off (still participates in count)
    if (d0 >= nc - 1) {
        if (t < MT) scores[b * NMAX + d0 + t] = NEGV;
        if (fused) fused_loss_tail(b, t, scores, dests, loss_out, cnt, s_u);
        return;
    }

    // dirn==1: cand occupies x[0:256) -> W1 k-rows [0:256) -> kb0=0; else kb0=8
    const int kb0 = (dirns[b] == 1) ? 0 : 8;

    // ---- stage cand tile (MT x 256 fp32 -> bf16 LDS, leading dim SA_LD) ----
    {
        const float4* src4 = (const float4*)nodes_hv + ((size_t)b * NMAX + d0) * (HH / 4);
        #pragma unroll
        for (int i = 0; i < (MT * HH / 4) / 512; ++i) {   // 8 iters
            int idx = t + i * 512;
            int row = idx >> 6, c4 = idx & 63;
            float4 v = src4[idx];
            ushort4 p;
            p.x = f2bf(v.x); p.y = f2bf(v.y); p.z = f2bf(v.z); p.w = f2bf(v.w);
            *(ushort4*)&s_u[row * SA_LD + c4 * 4] = p;
        }
    }
    __syncthreads();

    floatx4 acc[4][4];
    #pragma unroll
    for (int mb = 0; mb < 4; ++mb)
        #pragma unroll
        for (int tn = 0; tn < 4; ++tn)
            acc[mb][tn] = (floatx4){0.f, 0.f, 0.f, 0.f};

    // ---- layer 1: K = 256 (8 K-steps of 32), depth-1 weight prefetch ----
    {
        const ushort* wb1 = Wt1s + ((size_t)kb0 * 32 + wv * 4) * TILE + lane * 8;
        short8 bcur[4], bnxt[4];
        #pragma unroll
        for (int tn = 0; tn < 4; ++tn)
            bcur[tn] = *(const short8*)(wb1 + tn * TILE);
        #pragma unroll
        for (int ks = 0; ks < 8; ++ks) {
            if (ks < 7) {
                const ushort* wp = wb1 + (size_t)(ks + 1) * KSTR;
                #pragma unroll
                for (int tn = 0; tn < 4; ++tn)
                    bnxt[tn] = *(const short8*)(wp + tn * TILE);
            }
            __builtin_amdgcn_s_setprio(1);
            #pragma unroll
            for (int mb = 0; mb < 4; ++mb) {
                const short8 a = *(const short8*)&s_u[(mb * 16 + l15) * SA_LD + ks * 32 + q * 8];
                #pragma unroll
                for (int tn = 0; tn < 4; ++tn)
                    acc[mb][tn] = __builtin_amdgcn_mfma_f32_16x16x32_bf16(a, bcur[tn], acc[mb][tn], 0, 0, 0);
            }
            __builtin_amdgcn_s_setprio(0);
            #pragma unroll
            for (int tn = 0; tn < 4; ++tn)
                bcur[tn] = bnxt[tn];
        }
    }
    __syncthreads();   // all waves done reading cand tile before h1 overwrites union

    const int n0 = wv * 64;

    // ---- epilogue 1: h1 = relu(acc + v_b) -> fragment-tiled LDS ----
    // n = n0 + tn*16 + l15 -> ks_w = wv*2 + (tn>>1); qr = ((tn&1)<<1)+(l15>>3); j_w = l15&7
    {
        const int j_w = l15 & 7;
        #pragma unroll
        for (int tn = 0; tn < 4; ++tn) {
            const int n = n0 + tn * 16 + l15;
            const float v = v_ws[b * HID + n];
            const int ks_w = wv * 2 + (tn >> 1);
            const int qr   = ((tn & 1) << 1) + (l15 >> 3);
            #pragma unroll
            for (int mb = 0; mb < 4; ++mb) {
                #pragma unroll
                for (int r = 0; r < 4; ++r) {
                    float h = acc[mb][tn][r] + v;          // C/D: row=q*4+r, col=l15
                    h = h > 0.f ? h : 0.f;
                    s_u[((mb * 16 + ks_w) * 64 + qr * 16 + q * 4 + r) * 8 + j_w] = f2bf(h);
                }
            }
        }
    }
    __syncthreads();

    // ---- layer 2: K = 512 (16 K-steps), depth-1 weight prefetch ----
    #pragma unroll
    for (int mb = 0; mb < 4; ++mb)
        #pragma unroll
        for (int tn = 0; tn < 4; ++tn)
            acc[mb][tn] = (floatx4){0.f, 0.f, 0.f, 0.f};
    {
        const ushort* wb2 = Wt2s + ((size_t)wv * 4) * TILE + lane * 8;
        short8 bcur[4], bnxt[4];
        #pragma unroll
        for (int tn = 0; tn < 4; ++tn)
            bcur[tn] = *(const short8*)(wb2 + tn * TILE);
        #pragma unroll
        for (int ks = 0; ks < 16; ++ks) {
            if (ks < 15) {
                const ushort* wp = wb2 + (size_t)(ks + 1) * KSTR;
                #pragma unroll
                for (int tn = 0; tn < 4; ++tn)
                    bnxt[tn] = *(const short8*)(wp + tn * TILE);
            }
            __builtin_amdgcn_s_setprio(1);
            #pragma unroll
            for (int mb = 0; mb < 4; ++mb) {
                const short8 a = *(const short8*)&s_u[((mb * 16 + ks) * 64 + lane) * 8];
                #pragma unroll
                for (int tn = 0; tn < 4; ++tn)
                    acc[mb][tn] = __builtin_amdgcn_mfma_f32_16x16x32_bf16(a, bcur[tn], acc[mb][tn], 0, 0, 0);
            }
            __builtin_amdgcn_s_setprio(0);
            #pragma unroll
            for (int tn = 0; tn < 4; ++tn)
                bcur[tn] = bnxt[tn];
        }
    }

    // ---- epilogue 2: p = relu(acc + b2) . W3, reduce over n ----
    float p[4][4] = {{0,0,0,0},{0,0,0,0},{0,0,0,0},{0,0,0,0}};
    #pragma unroll
    for (int tn = 0; tn < 4; ++tn) {
        const int n  = n0 + tn * 16 + l15;
        const float bb = b2[n];
        const float w3 = W3[n];
        #pragma unroll
        for (int mb = 0; mb < 4; ++mb)
            #pragma unroll
            for (int r = 0; r < 4; ++r) {
                float h = acc[mb][tn][r] + bb;
                h = h > 0.f ? h : 0.f;
                p[mb][r] += h * w3;
            }
    }
    __syncthreads();   // h1 region dead; safe to reuse union for s_red
    float* s_red = (float*)s_u;   // [8 waves][MT]
    #pragma unroll
    for (int mb = 0; mb < 4; ++mb)
        #pragma unroll
        for (int r = 0; r < 4; ++r) {
            float v = p[mb][r];
            v += __shfl_xor(v, 1, 64);
            v += __shfl_xor(v, 2, 64);
            v += __shfl_xor(v, 4, 64);
            v += __shfl_xor(v, 8, 64);
            if (l15 == 0) s_red[wv * MT + mb * 16 + q * 4 + r] = v;
        }
    __syncthreads();
    if (t < MT) {
        float s = b3[0];
        #pragma unroll
        for (int w = 0; w < NW; ++w) s += s_red[w * MT + t];
        const int d = d0 + t;
        scores[b * NMAX + d] = (d < nc - 1) ? s : NEGV;
    }

    if (fused) fused_loss_tail(b, t, scores, dests, loss_out, cnt, s_u);
}

// ---------------------------------------------------------------------------
// Kernel 3 (fallback only, if ws has no room for counters):
// per-batch masked log-softmax NLL. grid = B, block = 256.
// ---------------------------------------------------------------------------
__global__ __launch_bounds__(256) void loss_kernel(
    const float* __restrict__ scores, const int* __restrict__ dests,
    float* __restrict__ out)
{
    const int b = blockIdx.x;
    const int t = threadIdx.x;
    __shared__ float red[4];

    const float s0 = scores[b * NMAX + t];
    const float s1 = scores[b * NMAX + t + 256];

    const int lane = t & 63, wv = t >> 6;

    float mx = fmaxf(s0, s1);
    #pragma unroll
    for (int off = 32; off > 0; off >>= 1) mx = fmaxf(mx, __shfl_down(mx, off, 64));
    if (lane == 0) red[wv] = mx;
    __syncthreads();
    mx = fmaxf(fmaxf(red[0], red[1]), fmaxf(red[2], red[3]));
    __syncthreads();

    float e = __expf(s0 - mx) + __expf(s1 - mx);
    #pragma unroll
    for (int off = 32; off > 0; off >>= 1) e += __shfl_down(e, off, 64);
    if (lane == 0) red[wv] = e;
    __syncthreads();

    if (t == 0) {
        const float sum = red[0] + red[1] + red[2] + red[3];
        const float sd = scores[b * NMAX + dests[b]];
        out[b] = -(sd - mx - logf(sum));
    }
}

// ---------------------------------------------------------------------------
extern "C" void kernel_launch(void* const* d_in, const int* in_sizes, int n_in,
                              void* d_out, int out_size, void* d_ws, size_t ws_size,
                              hipStream_t stream) {
    const float* nodes_hv    = (const float*)d_in[0];
    const float* class_cond  = (const float*)d_in[1];
    const float* W1          = (const float*)d_in[2];
    const float* b1          = (const float*)d_in[3];
    const float* W2          = (const float*)d_in[4];
    const float* b2          = (const float*)d_in[5];
    const float* W3          = (const float*)d_in[6];
    const float* b3          = (const float*)d_in[7];
    const int*   dirns       = (const int*)d_in[8];
    const int*   node_counts = (const int*)d_in[9];
    const int*   dests       = (const int*)d_in[10];
    float* out = (float*)d_out;

    // ws layout (16B-aligned):
    //   Wt1s: 512 KiB | Wt2s: 512 KiB | v_ws: 512 KiB | scores: 512 KiB | cnt: 1 KiB
    ushort* Wt1s   = (ushort*)d_ws;
    ushort* Wt2s   = Wt1s + 16 * KSTR;
    float*  v_ws   = (float*)(Wt2s + 16 * KSTR);
    float*  scores = v_ws + BB * HID;
    unsigned* cnt  = (unsigned*)(scores + BB * NMAX);

    const size_t need = (size_t)2 * 1024 * 1024 + BB * sizeof(unsigned);
    const int fused = (ws_size >= need) ? 1 : 0;

    if (fused) hipMemsetAsync(cnt, 0, BB * sizeof(unsigned), stream);

    prep_kernel<<<512, 512, 0, stream>>>(W1, W2, Wt1s, Wt2s,
                                         nodes_hv, class_cond, b1,
                                         dirns, node_counts, v_ws);
    mlp2<<<dim3(NMAX / MT, BB), 512, 0, stream>>>(
        nodes_hv, Wt1s, Wt2s, b2, W3, b3, dirns, node_counts, v_ws, scores,
        dests, out, cnt, fused);
    if (!fused)
        loss_kernel<<<BB, 256, 0, stream>>>(scores, dests, out);
}

// Round 13
// 288.882 us; speedup vs baseline: 1.4461x; 1.2659x over previous
//
#include <hip/hip_runtime.h>
#include <math.h>

// Problem constants
#define BB    256
#define NMAX  512
#define HH    256   // H
#define CC    64    // C
#define HID   512
#define NEGV  -1000000000.0f
#define MT    64    // d-rows per mlp block
#define NW    8     // waves per block (512 threads)
#define SA_LD 264   // A-tile leading dim: 256 + 8 pad (bf16 elems)
#define TILE  512   // ushorts per swizzled (16n x 32k) weight tile = 1KB
#define KSTR  (32 * TILE)  // ushorts per kb slab (32 n-tiles)

typedef __attribute__((ext_vector_type(8))) short short8;   // 8 bf16 = 4 VGPRs
typedef __attribute__((ext_vector_type(4))) float floatx4;  // MFMA C/D

// Native cast -> v_cvt_pk_bf16_f32 pairs (RNE, identical numerics to manual
// round-to-nearest-even bit math).
__device__ inline ushort f2bf(float x) {
    __bf16 b = (__bf16)x;
    return __builtin_bit_cast(ushort, b);
}

// ---------------------------------------------------------------------------
// Fused prep kernel, grid = 512 blocks x 512 threads (R10, verified):
//   blocks [0,128):   convert W1 k-rows [0,512) -> swizzled lane-order bf16
//   blocks [128,256): convert W2 -> swizzled lane-order bf16
//   blocks [256,512): per-batch base vector v_b (fp32 exact), 1 col/thread
// ---------------------------------------------------------------------------
__global__ __launch_bounds__(512) void prep_kernel(
    const float* __restrict__ W1, const float* __restrict__ W2,
    ushort* __restrict__ Wt1s, ushort* __restrict__ Wt2s,
    const float* __restrict__ nodes_hv, const float* __restrict__ class_cond,
    const float* __restrict__ b1,
    const int* __restrict__ dirns, const int* __restrict__ node_counts,
    float* __restrict__ v_ws)
{
    const int blk = blockIdx.x;
    const int t = threadIdx.x;

    __shared__ float s_conv[32][68];
    __shared__ float s_src[HH];
    __shared__ float s_cc[CC];

    if (blk < 256) {
        const float* W = (blk < 128) ? W1 : W2;
        ushort* out    = (blk < 128) ? Wt1s : Wt2s;
        const int bb  = blk & 127;
        const int kb  = bb >> 3, ntg = bb & 7;

        if (t < 256) {
            const int kl = t >> 3, nn = (t & 7) * 8;
            const float* src = W + (size_t)(kb * 32 + kl) * HID + ntg * 64 + nn;
            *(float4*)&s_conv[kl][nn]     = *(const float4*)src;
            *(float4*)&s_conv[kl][nn + 4] = *(const float4*)(src + 4);
        }
        __syncthreads();

        if (t < 256) {
            const int ntl = t >> 6, ls = t & 63;
            const int qs = ls >> 4, l15s = ls & 15;
            short8 o;
            #pragma unroll
            for (int j = 0; j < 8; ++j)
                o[j] = (short)f2bf(s_conv[qs * 8 + j][ntl * 16 + l15s]);
            const int nt = ntg * 4 + ntl;
            *(short8*)(out + ((size_t)(kb * 32 + nt)) * TILE + ls * 8) = o;
        }
    } else {
        const int b = blk - 256;
        const int nc   = node_counts[b];
        const int dirn = dirns[b];
        const int src_idx = nc - 1;

        if (t < HH) s_src[t] = nodes_hv[((size_t)b * NMAX + src_idx) * HH + t];
        else if (t < HH + CC) s_cc[t - HH] = class_cond[b * CC + (t - HH)];
        __syncthreads();

        const int srcoff = (dirn == 1) ? HH : 0;

        const int j = t;              // one HID column per thread
        float acc0 = b1[j];

        #pragma unroll 8
        for (int r = 0; r < HH; ++r)
            acc0 += s_src[r] * W1[(size_t)(srcoff + r) * HID + j];
        #pragma unroll 8
        for (int c = 0; c < CC; ++c)
            acc0 += s_cc[c] * W1[(size_t)(2 * HH + c) * HID + j];

        v_ws[b * HID + j] = acc0;
    }
}

// ---------------------------------------------------------------------------
// Kernel 2: MFMA MLP, M=64, 512 threads (8 waves). grid = (NMAX/MT, B).
// Verified R10 structure (286.8 µs total, mlp2 119 µs): full h1 in 64 KB LDS
// union, 2 blocks/CU, depth-1 register double-buffer of weight tiles,
// setprio around MFMA clusters, cvt_pk conversions.
// Register budget: acc(64 AGPR) + working(64 VGPR) = 128 = (512,4) cap.
// R8/R12 post-mortems: ANY restructure of acc/prefetch live ranges spills
// (12x / 2.2x slower). R13 post-mortem: fusing the loss via per-block
// device-scope threadfence+atomic serializes block retirement through the
// cross-XCD coherence point (+95 µs on mlp2). Keep loss as its own kernel.
// ---------------------------------------------------------------------------
__global__ __launch_bounds__(512, 4) void mlp2(
    const float* __restrict__ nodes_hv,
    const ushort* __restrict__ Wt1s, const ushort* __restrict__ Wt2s,
    const float* __restrict__ b2, const float* __restrict__ W3,
    const float* __restrict__ b3,
    const int* __restrict__ dirns, const int* __restrict__ node_counts,
    const float* __restrict__ v_ws, float* __restrict__ scores)
{
    const int b  = blockIdx.y;
    const int d0 = blockIdx.x * MT;
    const int t  = threadIdx.x;
    const int lane = t & 63, wv = t >> 6;     // wv in [0,8)
    const int l15 = lane & 15, q = lane >> 4;

    __shared__ ushort s_u[32768];   // 64 KB union

    const int nc = node_counts[b];

    // Block-uniform early exit: whole tile masked off
    if (d0 >= nc - 1) {
        if (t < MT) scores[b * NMAX + d0 + t] = NEGV;
        return;
    }

    // dirn==1: cand occupies x[0:256) -> W1 k-rows [0:256) -> kb0=0; else kb0=8
    const int kb0 = (dirns[b] == 1) ? 0 : 8;

    // ---- stage cand tile (MT x 256 fp32 -> bf16 LDS, leading dim SA_LD) ----
    {
        const float4* src4 = (const float4*)nodes_hv + ((size_t)b * NMAX + d0) * (HH / 4);
        #pragma unroll
        for (int i = 0; i < (MT * HH / 4) / 512; ++i) {   // 8 iters
            int idx = t + i * 512;
            int row = idx >> 6, c4 = idx & 63;
            float4 v = src4[idx];
            ushort4 p;
            p.x = f2bf(v.x); p.y = f2bf(v.y); p.z = f2bf(v.z); p.w = f2bf(v.w);
            *(ushort4*)&s_u[row * SA_LD + c4 * 4] = p;
        }
    }
    __syncthreads();

    floatx4 acc[4][4];
    #pragma unroll
    for (int mb = 0; mb < 4; ++mb)
        #pragma unroll
        for (int tn = 0; tn < 4; ++tn)
            acc[mb][tn] = (floatx4){0.f, 0.f, 0.f, 0.f};

    // ---- layer 1: K = 256 (8 K-steps of 32), depth-1 weight prefetch ----
    {
        const ushort* wb1 = Wt1s + ((size_t)kb0 * 32 + wv * 4) * TILE + lane * 8;
        short8 bcur[4], bnxt[4];
        #pragma unroll
        for (int tn = 0; tn < 4; ++tn)
            bcur[tn] = *(const short8*)(wb1 + tn * TILE);
        #pragma unroll
        for (int ks = 0; ks < 8; ++ks) {
            if (ks < 7) {
                const ushort* wp = wb1 + (size_t)(ks + 1) * KSTR;
                #pragma unroll
                for (int tn = 0; tn < 4; ++tn)
                    bnxt[tn] = *(const short8*)(wp + tn * TILE);
            }
            __builtin_amdgcn_s_setprio(1);
            #pragma unroll
            for (int mb = 0; mb < 4; ++mb) {
                const short8 a = *(const short8*)&s_u[(mb * 16 + l15) * SA_LD + ks * 32 + q * 8];
                #pragma unroll
                for (int tn = 0; tn < 4; ++tn)
                    acc[mb][tn] = __builtin_amdgcn_mfma_f32_16x16x32_bf16(a, bcur[tn], acc[mb][tn], 0, 0, 0);
            }
            __builtin_amdgcn_s_setprio(0);
            #pragma unroll
            for (int tn = 0; tn < 4; ++tn)
                bcur[tn] = bnxt[tn];
        }
    }
    __syncthreads();   // all waves done reading cand tile before h1 overwrites union

    const int n0 = wv * 64;

    // ---- epilogue 1: h1 = relu(acc + v_b) -> fragment-tiled LDS ----
    // n = n0 + tn*16 + l15 -> ks_w = wv*2 + (tn>>1); qr = ((tn&1)<<1)+(l15>>3); j_w = l15&7
    {
        const int j_w = l15 & 7;
        #pragma unroll
        for (int tn = 0; tn < 4; ++tn) {
            const int n = n0 + tn * 16 + l15;
            const float v = v_ws[b * HID + n];
            const int ks_w = wv * 2 + (tn >> 1);
            const int qr   = ((tn & 1) << 1) + (l15 >> 3);
            #pragma unroll
            for (int mb = 0; mb < 4; ++mb) {
                #pragma unroll
                for (int r = 0; r < 4; ++r) {
                    float h = acc[mb][tn][r] + v;          // C/D: row=q*4+r, col=l15
                    h = h > 0.f ? h : 0.f;
                    s_u[((mb * 16 + ks_w) * 64 + qr * 16 + q * 4 + r) * 8 + j_w] = f2bf(h);
                }
            }
        }
    }
    __syncthreads();

    // ---- layer 2: K = 512 (16 K-steps), depth-1 weight prefetch ----
    #pragma unroll
    for (int mb = 0; mb < 4; ++mb)
        #pragma unroll
        for (int tn = 0; tn < 4; ++tn)
            acc[mb][tn] = (floatx4){0.f, 0.f, 0.f, 0.f};
    {
        const ushort* wb2 = Wt2s + ((size_t)wv * 4) * TILE + lane * 8;
        short8 bcur[4], bnxt[4];
        #pragma unroll
        for (int tn = 0; tn < 4; ++tn)
            bcur[tn] = *(const short8*)(wb2 + tn * TILE);
        #pragma unroll
        for (int ks = 0; ks < 16; ++ks) {
            if (ks < 15) {
                const ushort* wp = wb2 + (size_t)(ks + 1) * KSTR;
                #pragma unroll
                for (int tn = 0; tn < 4; ++tn)
                    bnxt[tn] = *(const short8*)(wp + tn * TILE);
            }
            __builtin_amdgcn_s_setprio(1);
            #pragma unroll
            for (int mb = 0; mb < 4; ++mb) {
                const short8 a = *(const short8*)&s_u[((mb * 16 + ks) * 64 + lane) * 8];
                #pragma unroll
                for (int tn = 0; tn < 4; ++tn)
                    acc[mb][tn] = __builtin_amdgcn_mfma_f32_16x16x32_bf16(a, bcur[tn], acc[mb][tn], 0, 0, 0);
            }
            __builtin_amdgcn_s_setprio(0);
            #pragma unroll
            for (int tn = 0; tn < 4; ++tn)
                bcur[tn] = bnxt[tn];
        }
    }

    // ---- epilogue 2: p = relu(acc + b2) . W3, reduce over n ----
    float p[4][4] = {{0,0,0,0},{0,0,0,0},{0,0,0,0},{0,0,0,0}};
    #pragma unroll
    for (int tn = 0; tn < 4; ++tn) {
        const int n  = n0 + tn * 16 + l15;
        const float bb = b2[n];
        const float w3 = W3[n];
        #pragma unroll
        for (int mb = 0; mb < 4; ++mb)
            #pragma unroll
            for (int r = 0; r < 4; ++r) {
                float h = acc[mb][tn][r] + bb;
                h = h > 0.f ? h : 0.f;
                p[mb][r] += h * w3;
            }
    }
    __syncthreads();   // h1 region dead; safe to reuse union for s_red
    float* s_red = (float*)s_u;   // [8 waves][MT]
    #pragma unroll
    for (int mb = 0; mb < 4; ++mb)
        #pragma unroll
        for (int r = 0; r < 4; ++r) {
            float v = p[mb][r];
            v += __shfl_xor(v, 1, 64);
            v += __shfl_xor(v, 2, 64);
            v += __shfl_xor(v, 4, 64);
            v += __shfl_xor(v, 8, 64);
            if (l15 == 0) s_red[wv * MT + mb * 16 + q * 4 + r] = v;
        }
    __syncthreads();
    if (t < MT) {
        float s = b3[0];
        #pragma unroll
        for (int w = 0; w < NW; ++w) s += s_red[w * MT + t];
        const int d = d0 + t;
        scores[b * NMAX + d] = (d < nc - 1) ? s : NEGV;
    }
}

// ---------------------------------------------------------------------------
// Kernel 3: per-batch masked log-softmax NLL. grid = B, block = 256.
// (Separate kernel is CHEAPER than fusing: R13 measured +95 µs on mlp2 from
// per-block device-scope fence+atomic; this kernel costs ~3 µs.)
// ---------------------------------------------------------------------------
__global__ __launch_bounds__(256) void loss_kernel(
    const float* __restrict__ scores, const int* __restrict__ dests,
    float* __restrict__ out)
{
    const int b = blockIdx.x;
    const int t = threadIdx.x;
    __shared__ float red[4];

    const float s0 = scores[b * NMAX + t];
    const float s1 = scores[b * NMAX + t + 256];

    const int lane = t & 63, wv = t >> 6;

    float mx = fmaxf(s0, s1);
    #pragma unroll
    for (int off = 32; off > 0; off >>= 1) mx = fmaxf(mx, __shfl_down(mx, off, 64));
    if (lane == 0) red[wv] = mx;
    __syncthreads();
    mx = fmaxf(fmaxf(red[0], red[1]), fmaxf(red[2], red[3]));
    __syncthreads();

    float e = __expf(s0 - mx) + __expf(s1 - mx);
    #pragma unroll
    for (int off = 32; off > 0; off >>= 1) e += __shfl_down(e, off, 64);
    if (lane == 0) red[wv] = e;
    __syncthreads();

    if (t == 0) {
        const float sum = red[0] + red[1] + red[2] + red[3];
        const float sd = scores[b * NMAX + dests[b]];
        out[b] = -(sd - mx - logf(sum));
    }
}

// ---------------------------------------------------------------------------
extern "C" void kernel_launch(void* const* d_in, const int* in_sizes, int n_in,
                              void* d_out, int out_size, void* d_ws, size_t ws_size,
                              hipStream_t stream) {
    const float* nodes_hv    = (const float*)d_in[0];
    const float* class_cond  = (const float*)d_in[1];
    const float* W1          = (const float*)d_in[2];
    const float* b1          = (const float*)d_in[3];
    const float* W2          = (const float*)d_in[4];
    const float* b2          = (const float*)d_in[5];
    const float* W3          = (const float*)d_in[6];
    const float* b3          = (const float*)d_in[7];
    const int*   dirns       = (const int*)d_in[8];
    const int*   node_counts = (const int*)d_in[9];
    const int*   dests       = (const int*)d_in[10];
    float* out = (float*)d_out;

    // ws layout (16B-aligned):
    //   Wt1s: 512 KiB | Wt2s: 512 KiB | v_ws: 512 KiB | scores: 512 KiB
    ushort* Wt1s   = (ushort*)d_ws;
    ushort* Wt2s   = Wt1s + 16 * KSTR;
    float*  v_ws   = (float*)(Wt2s + 16 * KSTR);
    float*  scores = v_ws + BB * HID;

    prep_kernel<<<512, 512, 0, stream>>>(W1, W2, Wt1s, Wt2s,
                                         nodes_hv, class_cond, b1,
                                         dirns, node_counts, v_ws);
    mlp2<<<dim3(NMAX / MT, BB), 512, 0, stream>>>(
        nodes_hv, Wt1s, Wt2s, b2, W3, b3, dirns, node_counts, v_ws, scores);
    loss_kernel<<<BB, 256, 0, stream>>>(scores, dests, out);
}